// Round 9
// baseline (112.558 us; speedup 1.0000x reference)
//
#include <hip/hip_runtime.h>
#include <math.h>
#include <stdint.h>

#define GAMMA 0.7f
#define QCAP 3072

typedef __attribute__((ext_vector_type(8))) short short8v;   // 8 bf16
typedef __attribute__((ext_vector_type(4))) float f32x4;

__device__ __forceinline__ float sp_dev(float x) {
    return fmaxf(x, 0.0f) + log1pf(expf(-fabsf(x)));
}
__device__ __forceinline__ float gelu_exact(float x) {
    return 0.5f * x * (1.0f + erff(x * 0.70710678118654752f));
}
__device__ __forceinline__ uint16_t f2bf(float x) {
    union { float f; uint32_t u; } c; c.f = x;
    uint32_t u = c.u + 0x7FFFu + ((c.u >> 16) & 1u);
    return (uint16_t)(u >> 16);
}

// walk coefficients for motif m (k = 3+m), layer L, filter f
__device__ __forceinline__ void walk_coef(const float* __restrict__ W,
                                          const float* __restrict__ g,
                                          int f, int k, float* d) {
    float S[4][4], Y[4][4];
    for (int a = 0; a < k; a++)
        for (int b = 0; b < k; b++)
            S[a][b] = sp_dev(W[(f * k + a) * k + b]);
    for (int a = 0; a < k; a++)
        for (int b = 0; b < k; b++)
            Y[a][b] = (a == b) ? 0.0f : 0.5f * (S[a][b] + S[b][a]);
    for (int a = 0; a < k; a++) {
        float rs = 0.0f;
        for (int b = 0; b < k; b++) rs += Y[a][b];
        rs = fmaxf(rs, 1e-12f);
        for (int b = 0; b < k; b++) Y[a][b] /= rs;
    }
    float t1 = 0, t2 = 0, t3 = 0;
    for (int a = 0; a < k; a++) t1 += Y[a][a];
    for (int a = 0; a < k; a++)
        for (int b = 0; b < k; b++) t2 += Y[a][b] * Y[b][a];
    for (int a = 0; a < k; a++)
        for (int b = 0; b < k; b++)
            for (int c = 0; c < k; c++) t3 += Y[a][b] * Y[b][c] * Y[c][a];
    d[0] = GAMMA * sp_dev(g[0]) * t1;
    d[1] = GAMMA * GAMMA * sp_dev(g[1]) * t2;
    d[2] = GAMMA * GAMMA * GAMMA * sp_dev(g[2]) * t3;
}

// 4 lanes per instance; lane g loads row g of the (padded) 4x4 submatrix.
// Tri (K=3): row3=[0,0,0,1] -> traces corrected by -1. Writes dense cont.
template <int K>
__device__ __forceinline__ void contrib4(
    const float* __restrict__ A, int n, const int* __restrict__ idx,
    int li, int ginst, int lane, const float (*dc)[8][3],
    float* __restrict__ cont, int Itot) {
    int g = lane & 3;
    int base = lane & ~3;
    int mynode = (g < K) ? idx[li * K + g] : 0;
    int nb0 = __shfl(mynode, base + 0);
    int nb1 = __shfl(mynode, base + 1);
    int nb2 = __shfl(mynode, base + 2);
    int nb3 = (K == 4) ? __shfl(mynode, base + 3) : 0;

    float r0, r1, r2, r3;
    if (K == 3) {
        if (g < 3) {
            const float* Ar = A + (size_t)mynode * n;
            r0 = Ar[nb0]; r1 = Ar[nb1]; r2 = Ar[nb2]; r3 = 0.0f;
        } else {
            r0 = 0.0f; r1 = 0.0f; r2 = 0.0f; r3 = 1.0f;
        }
    } else {
        const float* Ar = A + (size_t)mynode * n;
        r0 = Ar[nb0]; r1 = Ar[nb1]; r2 = Ar[nb2]; r3 = Ar[nb3];
    }
    float rs = fmaxf(r0 + r1 + r2 + r3, 1e-12f);
    float inv = 1.0f / rs;
    r0 *= inv; r1 *= inv; r2 *= inv; r3 *= inv;

    float M[4][4];
#pragma unroll
    for (int b = 0; b < 4; b++) {
        M[b][0] = __shfl(r0, base + b);
        M[b][1] = __shfl(r1, base + b);
        M[b][2] = __shfl(r2, base + b);
        M[b][3] = __shfl(r3, base + b);
    }

    float t1 = M[0][0] + M[1][1] + M[2][2] + M[3][3];
    float t2 = 0.0f, t3 = 0.0f;
#pragma unroll
    for (int a = 0; a < 4; a++)
#pragma unroll
        for (int b = 0; b < 4; b++) {
            float ab = M[a][b];
            t2 += ab * M[b][a];
            float a3 = 0;
#pragma unroll
            for (int c = 0; c < 4; c++) a3 += M[b][c] * M[c][a];
            t3 += ab * a3;
        }
    if (K == 3) { t1 -= 1.0f; t2 -= 1.0f; t3 -= 1.0f; }

    const float kinv = 1.0f / (float)K;
#pragma unroll
    for (int L = 0; L < 2; L++) {
        float sims[8], mx = -1e30f;
#pragma unroll
        for (int f = 0; f < 8; f++) {
            sims[f] = dc[L][f][0] * t1 + dc[L][f][1] * t2 + dc[L][f][2] * t3;
            mx = fmaxf(mx, sims[f]);
        }
        float es[8], se = 0.0f;
#pragma unroll
        for (int f = 0; f < 8; f++) { es[f] = expf(sims[f] - mx); se += es[f]; }
        float sinv = 1.0f / se;
        float cn[8];
#pragma unroll
        for (int f = 0; f < 8; f++) cn[f] = es[f] * sinv * sims[f] * kinv;
        float p0 = (g == 0) ? cn[0] : (g == 1) ? cn[2] : (g == 2) ? cn[4] : cn[6];
        float p1 = (g == 0) ? cn[1] : (g == 1) ? cn[3] : (g == 2) ? cn[5] : cn[7];
        *(float2*)(cont + ((size_t)L * Itot + ginst) * 8 + 2 * g) = make_float2(p0, p1);
    }
}

// ===========================================================================
// K1: role-split grid (rowsum FIRST to warm L3 with A).
//   [0, BR)             : rowsum, 4 rows/block (one per wave)
//   [BR, BR+BT)         : tri contrib (4-lane, 64 inst/block)
//   [BR+BT, BR+BT+BCY)  : cyc contrib
//   [.., +BP)           : prep bf16 transposed weights
// ===========================================================================
__global__ __launch_bounds__(256) void k1_kernel(
    const float* __restrict__ A, const int* __restrict__ tri, const int* __restrict__ cyc,
    const float* __restrict__ Wt0, const float* __restrict__ Wc0, const float* __restrict__ g0,
    const float* __restrict__ Wt1, const float* __restrict__ Wc1, const float* __restrict__ g1,
    const float* __restrict__ w1_0, const float* __restrict__ w2_0,
    const float* __restrict__ w1_1, const float* __restrict__ w2_1,
    float* __restrict__ cont, float* __restrict__ H0,
    uint16_t* __restrict__ Wb10, uint16_t* __restrict__ Wb20,
    uint16_t* __restrict__ Wb11, uint16_t* __restrict__ Wb21,
    float* __restrict__ out, int n, int Itri, int Icyc, int BR, int BT, int BCY) {

    const int tid = threadIdx.x;
    const int bid = blockIdx.x;
    const int Itot = Itri + Icyc;
    const int lane = tid & 63;

    if (bid < BR) {
        // ---------------- rowsum: wave per row ----------------
        int row = bid * 4 + (tid >> 6);
        const float4* Ar = (const float4*)(A + (size_t)row * n);
        int n4 = n >> 2;
        float s = 0.0f;
        for (int i = lane; i < n4; i += 64) {
            float4 v = Ar[i];
            s += v.x + v.y + v.z + v.w;
        }
        for (int off = 32; off > 0; off >>= 1) s += __shfl_down(s, off);
        if (lane == 0) {
            H0[row] = s;
            out[(size_t)row * 257 + 256] = s;
        }
    } else if (bid < BR + BT + BCY) {
        // ---------------- contrib (4-lane) ----------------
        bool isTri = bid < BR + BT;
        __shared__ float dc[2][8][3];
        if (tid < 16) {
            int L = tid >> 3, f = tid & 7;
            const float* W = isTri ? (L ? Wt1 : Wt0) : (L ? Wc1 : Wc0);
            const float* g = L ? g1 : g0;
            walk_coef(W, g, f, isTri ? 3 : 4, &dc[L][f][0]);
        }
        __syncthreads();
        if (isTri) {
            int li = (bid - BR) * 64 + (tid >> 2);
            if (li < Itri)
                contrib4<3>(A, n, tri, li, li, lane, dc, cont, Itot);
        } else {
            int li = (bid - BR - BT) * 64 + (tid >> 2);
            if (li < Icyc)
                contrib4<4>(A, n, cyc, li, Itri + li, lane, dc, cont, Itot);
        }
    } else {
        // ---------------- prep: bf16 transposed weights ----------------
        int base = (bid - BR - BT - BCY) * 4096;
        for (int k = 0; k < 16; k++) {
            int idx = base + k * 256 + tid;
            if (idx >= 57344) break;
            if (idx < 4096) {
                int c = idx >> 5, kk = idx & 31;
                Wb10[idx] = (kk < 17) ? f2bf(w1_0[kk * 128 + c]) : 0;
            } else if (idx < 20480) {
                int e = idx - 4096; int c = e >> 7, kk = e & 127;
                Wb20[e] = f2bf(w2_0[kk * 128 + c]);
            } else if (idx < 40960) {
                int e = idx - 20480; int c = e / 160, kk = e % 160;
                Wb11[e] = (kk < 145) ? f2bf(w1_1[kk * 128 + c]) : 0;
            } else {
                int e = idx - 40960; int c = e >> 7, kk = e & 127;
                Wb21[e] = f2bf(w2_1[kk * 128 + c]);
            }
        }
    }
}

// ===========================================================================
// K2 (512 thr): per 16-row tile: scan membership -> drain cont into LDS phi ->
// LN0 -> G1_0 -> G2_0 (out cols 128..255) -> LN1 -> G1_1 -> G2_1 (cols 0..127)
// ===========================================================================
__global__ __launch_bounds__(512) void k2_kernel(
    const int* __restrict__ tri, const int* __restrict__ cyc,
    const float* __restrict__ cont, const float* __restrict__ H0,
    const float* __restrict__ lng0, const float* __restrict__ lnb0,
    const uint16_t* __restrict__ Wb10, const float* __restrict__ b1_0,
    const uint16_t* __restrict__ Wb20, const float* __restrict__ b2_0,
    const float* __restrict__ lng1, const float* __restrict__ lnb1,
    const uint16_t* __restrict__ Wb11, const float* __restrict__ b1_1,
    const uint16_t* __restrict__ Wb21, const float* __restrict__ b2_1,
    float* __restrict__ out, int n, int Itri, int Icyc) {

    // queue (scan/drain) overlays Xs/Hs/Zs (tail) -- disjoint lifetimes
    __shared__ __align__(16) char upool[18432];
    int* queue = (int*)upool;                                 // 12 KB used
    uint16_t (*Xs)[168] = (uint16_t(*)[168])upool;            // 5376 B
    uint16_t (*Hs)[136] = (uint16_t(*)[136])(upool + 5376);   // 4352 B
    float    (*Zs)[132] = (float(*)[132])(upool + 9728);      // 8448 B
    __shared__ float phi[2][16][16];
    __shared__ float h0s[16];
    __shared__ int qcnt;

    const int tid  = threadIdx.x;
    const int v0   = blockIdx.x * 16;
    const int lane = tid & 63;
    const int Itot = Itri + Icyc;

    // ---- init ----
    ((float*)phi)[tid] = 0.0f;
    if (tid == 0) qcnt = 0;
    if (tid < 16) h0s[tid] = H0[v0 + tid];
    __syncthreads();

    // ---- scan: membership test of all instances ----
    for (int base = 0; base < Itot; base += 512) {
        int inst = base + tid;
        if (inst >= Itot) break;
        int hit = 0;
        if (inst < Itri) {
            const int* p = tri + inst * 3;
#pragma unroll
            for (int j = 0; j < 3; j++) hit |= ((unsigned)(p[j] - v0) < 16u);
        } else {
            const int* p = cyc + (size_t)(inst - Itri) * 4;
#pragma unroll
            for (int j = 0; j < 4; j++) hit |= ((unsigned)(p[j] - v0) < 16u);
        }
        if (hit) {
            int q = atomicAdd(&qcnt, 1);
            if (q < QCAP) queue[q] = inst;
        }
    }
    __syncthreads();

    // ---- drain: item = (hit, L); read cont line, scatter into LDS phi ----
    {
        int qn = qcnt < QCAP ? qcnt : QCAP;
        for (int it = tid; it < 2 * qn; it += 512) {
            int qi = it >> 1, L = it & 1;
            int inst = queue[qi];
            bool isTri = inst < Itri;
            int K = isTri ? 3 : 4;
            int m = isTri ? 0 : 1;
            const int* p = isTri ? tri + inst * 3 : cyc + (size_t)(inst - Itri) * 4;
            const float* cp = cont + ((size_t)L * Itot + inst) * 8;
            float4 c0 = *(const float4*)cp;
            float4 c1 = *(const float4*)(cp + 4);
#pragma unroll
            for (int j = 0; j < 4; j++) {
                if (j >= K) break;
                int r = p[j] - v0;
                if ((unsigned)r < 16u) {
                    float* dst = &phi[L][r][m * 8];
                    atomicAdd(&dst[0], c0.x); atomicAdd(&dst[1], c0.y);
                    atomicAdd(&dst[2], c0.z); atomicAdd(&dst[3], c0.w);
                    atomicAdd(&dst[4], c1.x); atomicAdd(&dst[5], c1.y);
                    atomicAdd(&dst[6], c1.z); atomicAdd(&dst[7], c1.w);
                }
            }
        }
    }
    __syncthreads();

    // ---- LN0 -> Xs[:,0..31] ----
    {
        int r = tid >> 5;
        int j = tid & 31;
        float x = (j < 16) ? phi[0][r][j] : (j == 16 ? h0s[r] : 0.0f);
        float s1 = x, s2 = x * x;
        for (int o = 16; o > 0; o >>= 1) { s1 += __shfl_xor(s1, o); s2 += __shfl_xor(s2, o); }
        float mu = s1 / 17.0f;
        float rstd = rsqrtf(s2 / 17.0f - mu * mu + 1e-5f);
        Xs[r][j] = (j < 17) ? f2bf((x - mu) * rstd * lng0[j] + lnb0[j]) : (uint16_t)0;
    }
    __syncthreads();

    // ---- G1 layer0 (K=32) ----
    {
        int w8 = tid >> 6, lr = lane & 15, lg = lane >> 4;
        int col = w8 * 16 + lr;
        f32x4 acc = {0.f, 0.f, 0.f, 0.f};
        short8v a = *(const short8v*)&Xs[lr][lg * 8];
        short8v b = *(const short8v*)(Wb10 + (size_t)col * 32 + lg * 8);
        acc = __builtin_amdgcn_mfma_f32_16x16x32_bf16(a, b, acc, 0, 0, 0);
        float bias = b1_0[col];
#pragma unroll
        for (int i = 0; i < 4; i++)
            Hs[lg * 4 + i][col] = f2bf(gelu_exact(acc[i] + bias));
    }
    __syncthreads();

    // ---- G2 layer0 -> out[:,128..255] + Zs ----
    {
        int w8 = tid >> 6, lr = lane & 15, lg = lane >> 4;
        int col = w8 * 16 + lr;
        f32x4 acc = {0.f, 0.f, 0.f, 0.f};
#pragma unroll
        for (int ks = 0; ks < 4; ks++) {
            short8v a = *(const short8v*)&Hs[lr][ks * 32 + lg * 8];
            short8v b = *(const short8v*)(Wb20 + (size_t)col * 128 + ks * 32 + lg * 8);
            acc = __builtin_amdgcn_mfma_f32_16x16x32_bf16(a, b, acc, 0, 0, 0);
        }
        float bias = b2_0[col];
#pragma unroll
        for (int i = 0; i < 4; i++) {
            int row = lg * 4 + i;
            float val = acc[i] + bias;
            out[(size_t)(v0 + row) * 257 + 128 + col] = val;
            Zs[row][col] = val;
        }
    }
    __syncthreads();

    // ---- LN1 -> Xs[:,0..159] ----
    {
        int rr = tid >> 5;
        int t = tid & 31;
        float ph[5];
        float s1 = 0.0f, s2 = 0.0f;
#pragma unroll
        for (int s = 0; s < 5; s++) {
            int j = t + 32 * s;
            float x = 0.0f;
            if (j < 16) x = phi[1][rr][j];
            else if (j < 144) x = Zs[rr][j - 16];
            else if (j == 144) x = h0s[rr];
            ph[s] = x;
            if (j < 145) { s1 += x; s2 += x * x; }
        }
        for (int o = 16; o > 0; o >>= 1) { s1 += __shfl_xor(s1, o); s2 += __shfl_xor(s2, o); }
        float mu = s1 / 145.0f;
        float rstd = rsqrtf(s2 / 145.0f - mu * mu + 1e-5f);
#pragma unroll
        for (int s = 0; s < 5; s++) {
            int j = t + 32 * s;
            Xs[rr][j] = (j < 145) ? f2bf((ph[s] - mu) * rstd * lng1[j] + lnb1[j])
                                  : (uint16_t)0;
        }
    }
    __syncthreads();

    // ---- G1 layer1 (K=160) ----
    {
        int w8 = tid >> 6, lr = lane & 15, lg = lane >> 4;
        int col = w8 * 16 + lr;
        f32x4 acc = {0.f, 0.f, 0.f, 0.f};
#pragma unroll
        for (int ks = 0; ks < 5; ks++) {
            short8v a = *(const short8v*)&Xs[lr][ks * 32 + lg * 8];
            short8v b = *(const short8v*)(Wb11 + (size_t)col * 160 + ks * 32 + lg * 8);
            acc = __builtin_amdgcn_mfma_f32_16x16x32_bf16(a, b, acc, 0, 0, 0);
        }
        float bias = b1_1[col];
#pragma unroll
        for (int i = 0; i < 4; i++)
            Hs[lg * 4 + i][col] = f2bf(gelu_exact(acc[i] + bias));
    }
    __syncthreads();

    // ---- G2 layer1 -> out[:,0..127] ----
    {
        int w8 = tid >> 6, lr = lane & 15, lg = lane >> 4;
        int col = w8 * 16 + lr;
        f32x4 acc = {0.f, 0.f, 0.f, 0.f};
#pragma unroll
        for (int ks = 0; ks < 4; ks++) {
            short8v a = *(const short8v*)&Hs[lr][ks * 32 + lg * 8];
            short8v b = *(const short8v*)(Wb21 + (size_t)col * 128 + ks * 32 + lg * 8);
            acc = __builtin_amdgcn_mfma_f32_16x16x32_bf16(a, b, acc, 0, 0, 0);
        }
        float bias = b2_1[col];
#pragma unroll
        for (int i = 0; i < 4; i++) {
            int row = lg * 4 + i;
            out[(size_t)(v0 + row) * 257 + col] = acc[i] + bias;
        }
    }
}

extern "C" void kernel_launch(void* const* d_in, const int* in_sizes, int n_in,
                              void* d_out, int out_size, void* d_ws, size_t ws_size,
                              hipStream_t stream) {
    const float* A    = (const float*)d_in[0];
    const int*   tri  = (const int*)d_in[1];
    const int*   cyc  = (const int*)d_in[2];

    int n    = out_size / 257;          // 4096
    int Itri = in_sizes[1] / 3;         // 30000
    int Icyc = in_sizes[2] / 4;         // 15000
    int Itot = Itri + Icyc;

    float* ws = (float*)d_ws;
    float* H0   = ws;                                    // n
    float* cont = ws + n;                                // 2*Itot*8
    uint16_t* Wb10 = (uint16_t*)(cont + (size_t)2 * Itot * 8);  // 128*32
    uint16_t* Wb20 = Wb10 + 128 * 32;                    // 128*128
    uint16_t* Wb11 = Wb20 + 128 * 128;                   // 128*160
    uint16_t* Wb21 = Wb11 + 128 * 160;                   // 128*128
    float* out = (float*)d_out;

    int BR  = n / 4;                 // 1024 rowsum blocks (4 rows each)
    int BT  = (Itri + 63) / 64;      // 469 tri contrib blocks
    int BCY = (Icyc + 63) / 64;      // 235 cyc contrib blocks
    int BP  = 14;                    // prep blocks

    k1_kernel<<<BR + BT + BCY + BP, 256, 0, stream>>>(
        A, tri, cyc,
        (const float*)d_in[3], (const float*)d_in[4], (const float*)d_in[5],
        (const float*)d_in[12], (const float*)d_in[13], (const float*)d_in[14],
        (const float*)d_in[8], (const float*)d_in[10],
        (const float*)d_in[17], (const float*)d_in[19],
        cont, H0, Wb10, Wb20, Wb11, Wb21, out, n, Itri, Icyc, BR, BT, BCY);

    k2_kernel<<<n / 16, 512, 0, stream>>>(
        tri, cyc, cont, H0,
        (const float*)d_in[6], (const float*)d_in[7],
        Wb10, (const float*)d_in[9], Wb20, (const float*)d_in[11],
        (const float*)d_in[15], (const float*)d_in[16],
        Wb11, (const float*)d_in[18], Wb21, (const float*)d_in[20],
        out, n, Itri, Icyc);
}